// Round 7
// baseline (191.941 us; speedup 1.0000x reference)
//
#include <hip/hip_runtime.h>

#define BATCH 4096
#define D_IN 1024
#define D_OUT 1024
#define N_EXPERTS 8

#define TM 128
#define TN 128
#define TK 32
#define KSPLIT 2
#define KHALF (D_IN / KSPLIT)          // 512
#define NSTEPS (KHALF / TK)            // 16
#define MAX_TILES 39                   // sum ceil(c_e/128) <= 32 + 7

// ws int32 slots
#define WS_PERM    0       // [4096]
#define WS_STARTS  4096    // [9]
#define WS_TILE_E  4112    // [39]
#define WS_TILE_M  4160    // [39]
#define WS_NTILES  4224    // [1]

typedef __attribute__((ext_vector_type(8))) short short8;   // 8 x bf16
typedef __attribute__((ext_vector_type(4))) float f32x4;

// ---------------------------------------------------------------------------
// Atomic-free grouping (R6, proven) + fused meta passthrough. 128-row tiles.
// ---------------------------------------------------------------------------
__global__ __launch_bounds__(256) void group_kernel(
    const int* __restrict__ actions, const int* __restrict__ mxs,
    int* __restrict__ ws, float* __restrict__ out, int meta_mode) {
    __shared__ int h[256][N_EXPERTS];
    __shared__ int starts_s[N_EXPERTS];

    const int t = threadIdx.x;
    const int i0 = t * 16;
    int a_loc[16];
    int lc[N_EXPERTS];
#pragma unroll
    for (int e = 0; e < N_EXPERTS; ++e) lc[e] = 0;

    const int M = BATCH * D_OUT;
#pragma unroll
    for (int i = 0; i < 16; ++i) {
        const int a = actions[i0 + i];
        a_loc[i] = a;
        ++lc[a];
        if (meta_mode == 1) {
            out[M + i0 + i] = (float)mxs[i0 + i];
            out[M + BATCH + i0 + i] = (float)a;
        } else if (meta_mode == 2) {
            out[M + i0 + i] = (float)mxs[i0 + i];
            ((long long*)(out + M + BATCH))[i0 + i] = (long long)a;
        }
    }
#pragma unroll
    for (int e = 0; e < N_EXPERTS; ++e) h[t][e] = lc[e];
    __syncthreads();

    for (int d = 1; d < 256; d <<= 1) {
        int v[N_EXPERTS];
        const bool act = (t >= d);
        if (act) {
#pragma unroll
            for (int e = 0; e < N_EXPERTS; ++e) v[e] = h[t - d][e];
        }
        __syncthreads();
        if (act) {
#pragma unroll
            for (int e = 0; e < N_EXPERTS; ++e) h[t][e] += v[e];
        }
        __syncthreads();
    }

    if (t == 0) {
        int s = 0, nt = 0;
        for (int e = 0; e < N_EXPERTS; ++e) {
            const int c = h[255][e];
            starts_s[e] = s;
            ws[WS_STARTS + e] = s;
            for (int m0 = 0; m0 < c; m0 += TM) {
                ws[WS_TILE_E + nt] = e;
                ws[WS_TILE_M + nt] = m0;
                ++nt;
            }
            s += c;
        }
        ws[WS_STARTS + N_EXPERTS] = s;
        ws[WS_NTILES] = nt;
    }
    __syncthreads();

    int off[N_EXPERTS];
#pragma unroll
    for (int e = 0; e < N_EXPERTS; ++e)
        off[e] = starts_s[e] + h[t][e] - lc[e];
#pragma unroll
    for (int i = 0; i < 16; ++i) {
        const int a = a_loc[i];
        ws[WS_PERM + off[a]] = i0 + i;
        ++off[a];
    }
}

// ---------------------------------------------------------------------------
__global__ __launch_bounds__(256) void zero_kernel(float* __restrict__ out) {
    const int i = blockIdx.x * 256 + threadIdx.x;
    ((float4*)out)[i] = make_float4(0.f, 0.f, 0.f, 0.f);
}

// fp32 -> bf16 hi/lo split
__device__ __forceinline__ void cvt8(const float4 a, const float4 b,
                                     short8& h, short8& l) {
    float f[8] = {a.x, a.y, a.z, a.w, b.x, b.y, b.z, b.w};
#pragma unroll
    for (int i = 0; i < 8; ++i) {
        const unsigned u = __float_as_uint(f[i]);
        h[i] = (short)(u >> 16);
        const float r = f[i] - __uint_as_float(u & 0xffff0000u);
        l[i] = (short)(__float_as_uint(r) >> 16);
    }
}

// ---------------------------------------------------------------------------
// 128x128 split-K(2) double-buffered split-bf16 MFMA GEMM.
// Grid linear id: nx = id&7 (XCD-pinned n-slab -> W slab 4MB resident in L2),
// tix = (id>>3)%39, kh = (id>>3)/39. One barrier per K-step.
// 4 waves 2x2, each 64x64 = 4x4 MFMA tiles, 48 MFMA/step.
// LDS exactly 64 KB (2 x 32 KB buffers); perm rows read from global.
// ---------------------------------------------------------------------------
__global__ __launch_bounds__(256, 2) void moe_gemm(
    const float* __restrict__ xs, const float* __restrict__ W,
    const float* __restrict__ bias, const int* __restrict__ ws,
    float* __restrict__ out)
{
    const int id  = blockIdx.x;
    const int nx  = id & 7;
    const int rem = id >> 3;
    const int tix = rem % MAX_TILES;
    const int kh  = rem / MAX_TILES;
    if (tix >= ws[WS_NTILES]) return;
    const int e   = ws[WS_TILE_E + tix];
    const int m0  = ws[WS_TILE_M + tix];
    const int s0  = ws[WS_STARTS + e];
    const int cnt = ws[WS_STARTS + e + 1] - s0;
    const int n0  = nx * TN;
    const int kbase = kh * KHALF;
    const int* perm = ws + WS_PERM + s0 + m0;
    const int rem_rows = cnt - m0;     // valid rows in this tile (1..128)

    // [buf][plane A/B hi/lo][512 chunks][8 shorts] -> 4 arrays of 2x4096 shorts
    __shared__ short Ahi[2][TM * TK];
    __shared__ short Alo[2][TM * TK];
    __shared__ short Bhi[2][TN * TK];
    __shared__ short Blo[2][TN * TK];

    const int t = threadIdx.x;
    const int lane = t & 63;
    const int wave = t >> 6;
    const int wm = (wave & 1) * 64;
    const int wn = (wave >> 1) * 64;

    // staging: thread t owns chunks c = t and c = t+256 (of 512 per plane-pair)
    // chunk c: tile=c>>6, row_l=(c>>6)*16+(c&15), kq=(c&63)>>4
    const float* apt[2];
    const float* bpt[2];
#pragma unroll
    for (int i = 0; i < 2; ++i) {
        const int c = t + i * 256;
        const int row_l = ((c >> 6) << 4) | (c & 15);
        const int kq = (c & 63) >> 4;
        int ra = perm[(row_l < rem_rows) ? row_l : 0];
        apt[i] = xs + (size_t)ra * D_IN + kbase + kq * 8;
        bpt[i] = W + ((size_t)e << 20) + (size_t)(n0 + row_l) * D_IN + kbase + kq * 8;
    }
    const int st0 = t * 8;          // short offset of chunk t
    const int st1 = (t + 256) * 8;  // chunk t+256

    f32x4 acc[4][4];
#pragma unroll
    for (int mi = 0; mi < 4; ++mi)
#pragma unroll
        for (int nj = 0; nj < 4; ++nj)
            acc[mi][nj] = (f32x4){0.f, 0.f, 0.f, 0.f};

    float4 pa[2][2], pb[2][2];
    // prologue: load step 0, convert into buf 0
#pragma unroll
    for (int i = 0; i < 2; ++i) {
        pa[i][0] = *(const float4*)(apt[i]);
        pa[i][1] = *(const float4*)(apt[i] + 4);
        pb[i][0] = *(const float4*)(bpt[i]);
        pb[i][1] = *(const float4*)(bpt[i] + 4);
    }
    {
        short8 h, l;
        cvt8(pa[0][0], pa[0][1], h, l);
        *(short8*)&Ahi[0][st0] = h; *(short8*)&Alo[0][st0] = l;
        cvt8(pa[1][0], pa[1][1], h, l);
        *(short8*)&Ahi[0][st1] = h; *(short8*)&Alo[0][st1] = l;
        cvt8(pb[0][0], pb[0][1], h, l);
        *(short8*)&Bhi[0][st0] = h; *(short8*)&Blo[0][st0] = l;
        cvt8(pb[1][0], pb[1][1], h, l);
        *(short8*)&Bhi[0][st1] = h; *(short8*)&Blo[0][st1] = l;
    }

    for (int s = 0; s < NSTEPS; ++s) {
        const int cur = s & 1;
        __syncthreads();
        if (s + 1 < NSTEPS) {
            const int ko = (s + 1) * TK;
#pragma unroll
            for (int i = 0; i < 2; ++i) {
                pa[i][0] = *(const float4*)(apt[i] + ko);
                pa[i][1] = *(const float4*)(apt[i] + ko + 4);
                pb[i][0] = *(const float4*)(bpt[i] + ko);
                pb[i][1] = *(const float4*)(bpt[i] + ko + 4);
            }
        }
        short8 ah[4], al[4], bh[4], bl[4];
#pragma unroll
        for (int i2 = 0; i2 < 4; ++i2) {
            const int aoff = ((wm >> 4) + i2) * 512 + lane * 8;
            ah[i2] = *(const short8*)&Ahi[cur][aoff];
            al[i2] = *(const short8*)&Alo[cur][aoff];
            const int boff = ((wn >> 4) + i2) * 512 + lane * 8;
            bh[i2] = *(const short8*)&Bhi[cur][boff];
            bl[i2] = *(const short8*)&Blo[cur][boff];
        }
#pragma unroll
        for (int mi = 0; mi < 4; ++mi)
#pragma unroll
            for (int nj = 0; nj < 4; ++nj) {
                acc[mi][nj] = __builtin_amdgcn_mfma_f32_16x16x32_bf16(ah[mi], bh[nj], acc[mi][nj], 0, 0, 0);
                acc[mi][nj] = __builtin_amdgcn_mfma_f32_16x16x32_bf16(ah[mi], bl[nj], acc[mi][nj], 0, 0, 0);
                acc[mi][nj] = __builtin_amdgcn_mfma_f32_16x16x32_bf16(al[mi], bh[nj], acc[mi][nj], 0, 0, 0);
            }
        if (s + 1 < NSTEPS) {
            const int nxt = cur ^ 1;
            short8 h, l;
            cvt8(pa[0][0], pa[0][1], h, l);
            *(short8*)&Ahi[nxt][st0] = h; *(short8*)&Alo[nxt][st0] = l;
            cvt8(pa[1][0], pa[1][1], h, l);
            *(short8*)&Ahi[nxt][st1] = h; *(short8*)&Alo[nxt][st1] = l;
            cvt8(pb[0][0], pb[0][1], h, l);
            *(short8*)&Bhi[nxt][st0] = h; *(short8*)&Blo[nxt][st0] = l;
            cvt8(pb[1][0], pb[1][1], h, l);
            *(short8*)&Bhi[nxt][st1] = h; *(short8*)&Blo[nxt][st1] = l;
        }
    }

    // Epilogue: C/D layout col=lane&15, row=(lane>>4)*4+reg; atomicAdd into
    // zero-initialized out; bias added by kh==0 blocks only.
    const int cl = lane & 15;
    const int qd = lane >> 4;
    float bv[4];
#pragma unroll
    for (int nj = 0; nj < 4; ++nj)
        bv[nj] = (kh == 0) ? bias[e * D_OUT + n0 + wn + nj * 16 + cl] : 0.f;
#pragma unroll
    for (int mi = 0; mi < 4; ++mi) {
#pragma unroll
        for (int reg = 0; reg < 4; ++reg) {
            const int row_l = wm + mi * 16 + qd * 4 + reg;
            if (row_l < rem_rows) {
                const int r = perm[row_l];
                float* orow = out + (size_t)r * D_OUT + n0 + wn + cl;
#pragma unroll
                for (int nj = 0; nj < 4; ++nj)
                    atomicAdd(&orow[nj * 16], acc[mi][nj][reg] + bv[nj]);
            }
        }
    }
}

extern "C" void kernel_launch(void* const* d_in, const int* in_sizes, int n_in,
                              void* d_out, int out_size, void* d_ws, size_t ws_size,
                              hipStream_t stream) {
    const float* xs      = (const float*)d_in[0];
    const int*   mxs     = (const int*)d_in[1];
    const int*   actions = (const int*)d_in[2];
    const float* W       = (const float*)d_in[3];
    const float* bias    = (const float*)d_in[4];
    float* out = (float*)d_out;
    int*   ws  = (int*)d_ws;

    const int metaOff = BATCH * D_OUT;
    int meta_mode = 0;
    if (out_size >= metaOff + 3 * BATCH) meta_mode = 2;
    else if (out_size >= metaOff + 2 * BATCH) meta_mode = 1;

    zero_kernel<<<(BATCH * D_OUT) / (256 * 4), 256, 0, stream>>>(out);
    group_kernel<<<1, 256, 0, stream>>>(actions, mxs, ws, out, meta_mode);

    moe_gemm<<<8 * MAX_TILES * KSPLIT, 256, 0, stream>>>(xs, W, bias, ws, out);
}

// Round 8
// 184.329 us; speedup vs baseline: 1.0413x; 1.0413x over previous
//
#include <hip/hip_runtime.h>

#define BATCH 4096
#define D_IN 1024
#define D_OUT 1024
#define N_EXPERTS 8

#define TM 64
#define TN 128
#define TK 32
#define KSPLIT 2
#define KHALF (D_IN / KSPLIT)          // 512
#define NSTEPS (KHALF / TK)            // 16
#define MAX_TILES 71                   // sum ceil(c_e/64) <= 64 + 7

// ws int32 slots
#define WS_PERM    0       // [4096]
#define WS_STARTS  4096    // [9]
#define WS_TILE_E  4112    // [71]
#define WS_TILE_M  4200    // [71]
#define WS_NTILES  4288    // [1]

typedef __attribute__((ext_vector_type(8))) short short8;   // 8 x bf16
typedef __attribute__((ext_vector_type(4))) float f32x4;

// ---------------------------------------------------------------------------
// Atomic-free grouping (R6, proven) + fused meta passthrough. 64-row tiles.
// ---------------------------------------------------------------------------
__global__ __launch_bounds__(256) void group_kernel(
    const int* __restrict__ actions, const int* __restrict__ mxs,
    int* __restrict__ ws, float* __restrict__ out, int meta_mode) {
    __shared__ int h[256][N_EXPERTS];
    __shared__ int starts_s[N_EXPERTS];

    const int t = threadIdx.x;
    const int i0 = t * 16;
    int a_loc[16];
    int lc[N_EXPERTS];
#pragma unroll
    for (int e = 0; e < N_EXPERTS; ++e) lc[e] = 0;

    const int M = BATCH * D_OUT;
#pragma unroll
    for (int i = 0; i < 16; ++i) {
        const int a = actions[i0 + i];
        a_loc[i] = a;
        ++lc[a];
        if (meta_mode == 1) {
            out[M + i0 + i] = (float)mxs[i0 + i];
            out[M + BATCH + i0 + i] = (float)a;
        } else if (meta_mode == 2) {
            out[M + i0 + i] = (float)mxs[i0 + i];
            ((long long*)(out + M + BATCH))[i0 + i] = (long long)a;
        }
    }
#pragma unroll
    for (int e = 0; e < N_EXPERTS; ++e) h[t][e] = lc[e];
    __syncthreads();

    for (int d = 1; d < 256; d <<= 1) {
        int v[N_EXPERTS];
        const bool act = (t >= d);
        if (act) {
#pragma unroll
            for (int e = 0; e < N_EXPERTS; ++e) v[e] = h[t - d][e];
        }
        __syncthreads();
        if (act) {
#pragma unroll
            for (int e = 0; e < N_EXPERTS; ++e) h[t][e] += v[e];
        }
        __syncthreads();
    }

    if (t == 0) {
        int s = 0, nt = 0;
        for (int e = 0; e < N_EXPERTS; ++e) {
            const int c = h[255][e];
            starts_s[e] = s;
            ws[WS_STARTS + e] = s;
            for (int m0 = 0; m0 < c; m0 += TM) {
                ws[WS_TILE_E + nt] = e;
                ws[WS_TILE_M + nt] = m0;
                ++nt;
            }
            s += c;
        }
        ws[WS_STARTS + N_EXPERTS] = s;
        ws[WS_NTILES] = nt;
    }
    __syncthreads();

    int off[N_EXPERTS];
#pragma unroll
    for (int e = 0; e < N_EXPERTS; ++e)
        off[e] = starts_s[e] + h[t][e] - lc[e];
#pragma unroll
    for (int i = 0; i < 16; ++i) {
        const int a = a_loc[i];
        ws[WS_PERM + off[a]] = i0 + i;
        ++off[a];
    }
}

// ---------------------------------------------------------------------------
__global__ __launch_bounds__(256) void zero_kernel(float* __restrict__ out) {
    const int i = blockIdx.x * 256 + threadIdx.x;
    ((float4*)out)[i] = make_float4(0.f, 0.f, 0.f, 0.f);
}

// fp32 -> bf16 hi/lo split
__device__ __forceinline__ void cvt8(const float4 a, const float4 b,
                                     short8& h, short8& l) {
    float f[8] = {a.x, a.y, a.z, a.w, b.x, b.y, b.z, b.w};
#pragma unroll
    for (int i = 0; i < 8; ++i) {
        const unsigned u = __float_as_uint(f[i]);
        h[i] = (short)(u >> 16);
        const float r = f[i] - __uint_as_float(u & 0xffff0000u);
        l[i] = (short)(__float_as_uint(r) >> 16);
    }
}

// ---------------------------------------------------------------------------
// Split-bf16 MFMA GEMM: R2 traffic shape (64x128, TK=32) + split-K(2).
// Grid 8n x 71t x 2k = 1136 light blocks (~4.4/CU). Staging is thread-linear:
// thread t writes LDS short-offset 8t (== fragment-major order for this
// shape) -> conflict-free writes; fragment reads 16B/lane contiguous.
// 4 waves 2x2: each 32x64 quadrant = 2x4 MFMA tiles x 3 MFMA = 24/step.
// Epilogue atomicAdd (out zeroed); bias added by kh==0.
// ---------------------------------------------------------------------------
__global__ __launch_bounds__(256) void moe_gemm(
    const float* __restrict__ xs, const float* __restrict__ W,
    const float* __restrict__ bias, const int* __restrict__ ws,
    float* __restrict__ out)
{
    const int id  = blockIdx.x;
    const int nx  = id & 7;
    const int rem = id >> 3;
    const int tix = rem % MAX_TILES;
    const int kh  = rem / MAX_TILES;
    if (tix >= ws[WS_NTILES]) return;
    const int e   = ws[WS_TILE_E + tix];
    const int m0  = ws[WS_TILE_M + tix];
    const int s0  = ws[WS_STARTS + e];
    const int cnt = ws[WS_STARTS + e + 1] - s0;
    const int n0  = nx * TN;
    const int kbase = kh * KHALF;
    const int* perm = ws + WS_PERM + s0 + m0;
    const int rem_rows = cnt - m0;     // valid rows in this tile (1..64)

    __shared__ short Ahi[TM * TK];   // 4 KB
    __shared__ short Alo[TM * TK];
    __shared__ short Bhi[TN * TK];   // 8 KB
    __shared__ short Blo[TN * TK];

    const int t = threadIdx.x;
    const int lane = t & 63;
    const int wave = t >> 6;
    const int wm = (wave & 1) * 32;
    const int wn = (wave >> 1) * 64;

    // A chunk t (0..255): tile=t>>6, row=(t&15), kq=(t>>4)&3 -> LDS offset 8t
    // B chunks t and t+256: same decode over 8 tiles.
    const int arow_l = ((t >> 6) << 4) | (t & 15);
    const int kq = (t >> 4) & 3;
    const int ra = perm[(arow_l < rem_rows) ? arow_l : 0];
    const float* ap = xs + (size_t)ra * D_IN + kbase + kq * 8;
    const float* bp0;
    const float* bp1;
    {
        const int c0 = t;
        const int row0 = ((c0 >> 6) << 4) | (c0 & 15);
        bp0 = W + ((size_t)e << 20) + (size_t)(n0 + row0) * D_IN + kbase + ((c0 >> 4) & 3) * 8;
        const int c1 = t + 256;
        const int row1 = ((c1 >> 6) << 4) | (c1 & 15);
        bp1 = W + ((size_t)e << 20) + (size_t)(n0 + row1) * D_IN + kbase + ((c1 >> 4) & 3) * 8;
    }
    const int st0 = t * 8;
    const int st1 = (t + 256) * 8;

    f32x4 acc[2][4];
#pragma unroll
    for (int mi = 0; mi < 2; ++mi)
#pragma unroll
        for (int nj = 0; nj < 4; ++nj)
            acc[mi][nj] = (f32x4){0.f, 0.f, 0.f, 0.f};

    for (int s = 0; s < NSTEPS; ++s) {
        const int k0 = s * TK;
        __syncthreads();
        {
            const float4 a0 = *(const float4*)(ap + k0);
            const float4 a1 = *(const float4*)(ap + k0 + 4);
            const float4 b00 = *(const float4*)(bp0 + k0);
            const float4 b01 = *(const float4*)(bp0 + k0 + 4);
            const float4 b10 = *(const float4*)(bp1 + k0);
            const float4 b11 = *(const float4*)(bp1 + k0 + 4);
            short8 h, l;
            cvt8(a0, a1, h, l);
            *(short8*)&Ahi[st0] = h; *(short8*)&Alo[st0] = l;
            cvt8(b00, b01, h, l);
            *(short8*)&Bhi[st0] = h; *(short8*)&Blo[st0] = l;
            cvt8(b10, b11, h, l);
            *(short8*)&Bhi[st1] = h; *(short8*)&Blo[st1] = l;
        }
        __syncthreads();

        short8 ah[2], al[2], bh[4], bl[4];
#pragma unroll
        for (int i2 = 0; i2 < 2; ++i2) {
            const int aoff = ((wm >> 4) + i2) * 512 + lane * 8;
            ah[i2] = *(const short8*)&Ahi[aoff];
            al[i2] = *(const short8*)&Alo[aoff];
        }
#pragma unroll
        for (int i2 = 0; i2 < 4; ++i2) {
            const int boff = ((wn >> 4) + i2) * 512 + lane * 8;
            bh[i2] = *(const short8*)&Bhi[boff];
            bl[i2] = *(const short8*)&Blo[boff];
        }
#pragma unroll
        for (int mi = 0; mi < 2; ++mi)
#pragma unroll
            for (int nj = 0; nj < 4; ++nj) {
                acc[mi][nj] = __builtin_amdgcn_mfma_f32_16x16x32_bf16(ah[mi], bh[nj], acc[mi][nj], 0, 0, 0);
                acc[mi][nj] = __builtin_amdgcn_mfma_f32_16x16x32_bf16(ah[mi], bl[nj], acc[mi][nj], 0, 0, 0);
                acc[mi][nj] = __builtin_amdgcn_mfma_f32_16x16x32_bf16(al[mi], bh[nj], acc[mi][nj], 0, 0, 0);
            }
    }

    // Epilogue: C/D layout col=lane&15, row=(lane>>4)*4+reg; atomic accumulate.
    const int cl = lane & 15;
    const int qd = lane >> 4;
    float bv[4];
#pragma unroll
    for (int nj = 0; nj < 4; ++nj)
        bv[nj] = (kh == 0) ? bias[e * D_OUT + n0 + wn + nj * 16 + cl] : 0.f;
#pragma unroll
    for (int mi = 0; mi < 2; ++mi) {
#pragma unroll
        for (int reg = 0; reg < 4; ++reg) {
            const int row_l = wm + mi * 16 + qd * 4 + reg;
            if (row_l < rem_rows) {
                const int r = perm[row_l];
                float* orow = out + (size_t)r * D_OUT + n0 + wn + cl;
#pragma unroll
                for (int nj = 0; nj < 4; ++nj)
                    atomicAdd(&orow[nj * 16], acc[mi][nj][reg] + bv[nj]);
            }
        }
    }
}

extern "C" void kernel_launch(void* const* d_in, const int* in_sizes, int n_in,
                              void* d_out, int out_size, void* d_ws, size_t ws_size,
                              hipStream_t stream) {
    const float* xs      = (const float*)d_in[0];
    const int*   mxs     = (const int*)d_in[1];
    const int*   actions = (const int*)d_in[2];
    const float* W       = (const float*)d_in[3];
    const float* bias    = (const float*)d_in[4];
    float* out = (float*)d_out;
    int*   ws  = (int*)d_ws;

    const int metaOff = BATCH * D_OUT;
    int meta_mode = 0;
    if (out_size >= metaOff + 3 * BATCH) meta_mode = 2;
    else if (out_size >= metaOff + 2 * BATCH) meta_mode = 1;

    zero_kernel<<<(BATCH * D_OUT) / (256 * 4), 256, 0, stream>>>(out);
    group_kernel<<<1, 256, 0, stream>>>(actions, mxs, ws, out, meta_mode);

    moe_gemm<<<8 * MAX_TILES * KSPLIT, 256, 0, stream>>>(xs, W, bias, ws, out);
}